// Round 13
// baseline (399.893 us; speedup 1.0000x reference)
//
#include <hip/hip_runtime.h>
#include <hip/hip_bf16.h>
#include <math.h>

// NoisyTopkRouter: rows=32768, D=4096, E=64, k=8.
// R13: barrier-free, LDS-free main loop. Wave = 16 rows x 64 vcols x K/2.
// h: per-lane direct global loads in A-frag layout (zero redundancy, 2-deep
// reg prefetch). W: per-lane direct loads from L2-resident fp16x2 image with
// j-pair register ping-pong prefetch. No s_barrier in the loop; one
// __syncthreads before the cross-ks LDS reduction + fused epilogue.
// Output (fp32): gates[rows*64] | ix[rows*8] | full[rows*64]

typedef __attribute__((ext_vector_type(8))) _Float16 f16x8;
typedef __attribute__((ext_vector_type(4))) float f32x4;
typedef unsigned int u32;

#define D_DIM 4096
#define WSTEP_BYTES 16384   // per-step W image: 2 planes x 8KB

__device__ __forceinline__ float softplus_f(float x) {
    return fmaxf(x, 0.0f) + log1pf(expf(-fabsf(x)));
}

#define MFMA16F(A, B, C) __builtin_amdgcn_mfma_f32_16x16x32_f16((A), (B), (C), 0, 0, 0)

// ---- W pre-conversion (unchanged): 2 fp16 planes (p0=f16(w), p1=f16((w-p0)*2048)),
// per-step 16KB image, chunk-swizzled sc = c4 ^ ((vrow>>2)&3)
__global__ __launch_bounds__(256)
void wconv_kernel(const float* __restrict__ Ww, const float* __restrict__ Wn,
                  char* __restrict__ Wp)
{
    const int bid = blockIdx.x;            // 256 blocks
    const int kc = bid >> 1, half = bid & 1;
    const int t = threadIdx.x;
    const int vrow = half * 64 + (t >> 2);
    const int c4 = t & 3;
    const float* src = (vrow < 64) ? (Ww + (size_t)vrow * D_DIM)
                                   : (Wn + (size_t)(vrow - 64) * D_DIM);
    const float4 a = *reinterpret_cast<const float4*>(src + kc * 32 + c4 * 8);
    const float4 b = *reinterpret_cast<const float4*>(src + kc * 32 + c4 * 8 + 4);
    const float f[8] = {a.x, a.y, a.z, a.w, b.x, b.y, b.z, b.w};
    union { _Float16 h[8]; uint4 q; } P0, P1;
#pragma unroll
    for (int i = 0; i < 8; ++i) {
        _Float16 lo = (_Float16)f[i];
        P0.h[i] = lo;
        P1.h[i] = (_Float16)((f[i] - (float)lo) * 2048.0f);
    }
    const int sc = c4 ^ ((vrow >> 2) & 3);
    char* dst = Wp + (size_t)kc * WSTEP_BYTES + vrow * 64 + sc * 16;
    *reinterpret_cast<uint4*>(dst)        = P0.q;
    *reinterpret_cast<uint4*>(dst + 8192) = P1.q;
}

__global__ __launch_bounds__(256, 4)
void router_kernel(const float* __restrict__ h,
                   const float* __restrict__ bw,
                   const float* __restrict__ bn,
                   const float* __restrict__ noise,
                   const char* __restrict__ Wp,
                   float* __restrict__ out_gates,
                   float* __restrict__ out_ix,
                   float* __restrict__ out_full)
{
    __shared__ float plds[2][16][132];     // 16.9 KB, epilogue only

    const int t = threadIdx.x;
    const int lane = t & 63, w = t >> 6;   // 4 waves
    const int ks = w >> 1, cs = w & 1;     // K-half, vcol-half
    const int c = lane & 15, kg = lane >> 4;
    const int row0 = blockIdx.x * 16;      // 2048 blocks

    // h: lane -> row (row0+c), k = ks*2048 + step*32 + kg*8
    const float* hp = h + (size_t)(row0 + c) * D_DIM + ks * 2048 + kg * 8;
    // W image base for this wave's K-half
    const char* wb = Wp + (size_t)(ks * 64) * WSTEP_BYTES;
    // per-lane fragment offsets (j 0..3, plane 0/1)
    int woff[8];
#pragma unroll
    for (int j = 0; j < 4; ++j) {
        const int vrow = cs * 64 + j * 16 + c;
        const int sw = (kg ^ ((vrow >> 2) & 3)) * 16;
        woff[2 * j]     = vrow * 64 + sw;
        woff[2 * j + 1] = 8192 + vrow * 64 + sw;
    }

    f32x4 sA[4], aM[4];
#pragma unroll
    for (int j = 0; j < 4; ++j) { sA[j] = (f32x4)0.0f; aM[j] = (f32x4)0.0f; }

    // ---- prologue: step-0 W frags + step-0/1 h ----
    f16x8 W0a = *reinterpret_cast<const f16x8*>(wb + woff[0]);
    f16x8 W0b = *reinterpret_cast<const f16x8*>(wb + woff[1]);
    f16x8 W1a = *reinterpret_cast<const f16x8*>(wb + woff[2]);
    f16x8 W1b = *reinterpret_cast<const f16x8*>(wb + woff[3]);
    f16x8 W2a = *reinterpret_cast<const f16x8*>(wb + woff[4]);
    f16x8 W2b = *reinterpret_cast<const f16x8*>(wb + woff[5]);
    f16x8 W3a = *reinterpret_cast<const f16x8*>(wb + woff[6]);
    f16x8 W3b = *reinterpret_cast<const f16x8*>(wb + woff[7]);
    float4 hx = *reinterpret_cast<const float4*>(hp);
    float4 hy = *reinterpret_cast<const float4*>(hp + 4);
    float4 nx = *reinterpret_cast<const float4*>(hp + 32);
    float4 ny = *reinterpret_cast<const float4*>(hp + 36);

#pragma unroll 2
    for (int s = 0; s < 64; ++s) {
        // split current h (8 fp32) -> fp16x2 A-fragments
        f16x8 A0, A1;
        {
            const float f[8] = {hx.x, hx.y, hx.z, hx.w, hy.x, hy.y, hy.z, hy.w};
#pragma unroll
            for (int i = 0; i < 8; ++i) {
                _Float16 lo = (_Float16)f[i];
                A0[i] = lo;
                A1[i] = (_Float16)((f[i] - (float)lo) * 2048.0f);
            }
        }

        const int sn = (s + 1 < 64) ? s + 1 : 63;           // clamped (redundant tail loads)
        const char* wn = wb + (size_t)sn * WSTEP_BYTES;

        // j0,j1 consume, then reload those regs with step s+1 frags
        sA[0] = MFMA16F(A0, W0a, sA[0]);
        aM[0] = MFMA16F(A0, W0b, aM[0]);
        aM[0] = MFMA16F(A1, W0a, aM[0]);
        sA[1] = MFMA16F(A0, W1a, sA[1]);
        aM[1] = MFMA16F(A0, W1b, aM[1]);
        aM[1] = MFMA16F(A1, W1a, aM[1]);
        W0a = *reinterpret_cast<const f16x8*>(wn + woff[0]);
        W0b = *reinterpret_cast<const f16x8*>(wn + woff[1]);
        W1a = *reinterpret_cast<const f16x8*>(wn + woff[2]);
        W1b = *reinterpret_cast<const f16x8*>(wn + woff[3]);

        // j2,j3 consume, then reload
        sA[2] = MFMA16F(A0, W2a, sA[2]);
        aM[2] = MFMA16F(A0, W2b, aM[2]);
        aM[2] = MFMA16F(A1, W2a, aM[2]);
        sA[3] = MFMA16F(A0, W3a, sA[3]);
        aM[3] = MFMA16F(A0, W3b, aM[3]);
        aM[3] = MFMA16F(A1, W3a, aM[3]);
        W2a = *reinterpret_cast<const f16x8*>(wn + woff[4]);
        W2b = *reinterpret_cast<const f16x8*>(wn + woff[5]);
        W3a = *reinterpret_cast<const f16x8*>(wn + woff[6]);
        W3b = *reinterpret_cast<const f16x8*>(wn + woff[7]);

        // rotate h prefetch (2-deep)
        hx = nx; hy = ny;
        const int s2 = (s + 2 < 64) ? s + 2 : 63;
        nx = *reinterpret_cast<const float4*>(hp + s2 * 32);
        ny = *reinterpret_cast<const float4*>(hp + s2 * 32 + 4);
    }

    // ---- cross-ks reduction staging ----
    // C/D layout: col = lane&15 (-> vcol cs*64+j*16+c), row = kg*4 + e
#pragma unroll
    for (int j = 0; j < 4; ++j)
#pragma unroll
        for (int e = 0; e < 4; ++e)
            plds[ks][kg * 4 + e][cs * 64 + j * 16 + c] =
                sA[j][e] + aM[j][e] * 4.8828125e-4f;   // + mid-term * 2^-11
    __syncthreads();

    // ---- noisy + top-8 + softmaxes: wave w -> rows w*4..w*4+3, lane = expert ----
    const float bwv = bw[lane];
    const float bnv = bn[lane];
    for (int q = 0; q < 4; ++q) {
        const int lrow = w * 4 + q;
        const int grow = row0 + lrow;
        const float lwv = plds[0][lrow][lane]      + plds[1][lrow][lane]      + bwv;
        const float lnv = plds[0][lrow][64 + lane] + plds[1][lrow][64 + lane] + bnv;
        const float nz  = noise[(size_t)grow * 64 + lane];
        const float v   = lwv + nz * softplus_f(lnv);

        float cur2 = v;
        float m8 = 0.0f;
        int winIdx = 0;
        bool picked = false;
#pragma unroll
        for (int r = 0; r < 8; ++r) {
            float bvv = cur2;
            int   bi  = lane;
#pragma unroll
            for (int off = 32; off; off >>= 1) {
                const float ov = __shfl_xor(bvv, off);
                const int   oi = __shfl_xor(bi, off);
                if (ov > bvv || (ov == bvv && oi < bi)) { bvv = ov; bi = oi; }
            }
            if (r == 0) m8 = bvv;
            if (lane == r) winIdx = bi;
            if (lane == bi) { picked = true; cur2 = -INFINITY; }
        }

        const float pf = expf(v - m8);
        const float pg = picked ? pf : 0.0f;
        float sf = pf, sg = pg;
#pragma unroll
        for (int off = 32; off; off >>= 1) {
            sf += __shfl_xor(sf, off);
            sg += __shfl_xor(sg, off);
        }

        out_full [(size_t)grow * 64 + lane] = pf / sf;
        out_gates[(size_t)grow * 64 + lane] = pg / sg;
        if (lane < 8) out_ix[(size_t)grow * 8 + lane] = (float)winIdx;
    }
}

extern "C" void kernel_launch(void* const* d_in, const int* in_sizes, int n_in,
                              void* d_out, int out_size, void* d_ws, size_t ws_size,
                              hipStream_t stream) {
    const float* h  = (const float*)d_in[0];
    const float* Ww = (const float*)d_in[1];
    const float* bw = (const float*)d_in[2];
    const float* Wn = (const float*)d_in[3];
    const float* bn = (const float*)d_in[4];
    const float* nz = (const float*)d_in[5];

    const int rows = in_sizes[5] / 64;   // 32768

    float* out = (float*)d_out;
    float* og = out;
    float* oi = out + (size_t)rows * 64;
    float* of = out + (size_t)rows * 64 + (size_t)rows * 8;

    char* Wp = (char*)d_ws;   // 128 steps * 16384 B = 2 MB

    hipLaunchKernelGGL(wconv_kernel, dim3(256), dim3(256), 0, stream, Ww, Wn, Wp);
    hipLaunchKernelGGL(router_kernel, dim3(rows / 16), dim3(256), 0, stream,
                       h, bw, bn, nz, Wp, og, oi, of);
}

// Round 14
// 242.824 us; speedup vs baseline: 1.6468x; 1.6468x over previous
//
#include <hip/hip_runtime.h>
#include <hip/hip_bf16.h>
#include <math.h>

// NoisyTopkRouter: rows=32768, D=4096, E=64, k=8.
// R14: operand swap. A = W (per-lane from L2-resident fp16x2 image, coalesced,
// L1-shared per CU, short ping-pong prefetch); B = h (reg-staged, split once,
// tiny LDS planes, double-buffered). BK=64 -> 64 steps, 1 raw s_barrier each,
// W loads free-fly across barriers. 256 thr, BM=32, 4 waves x 32 vcols.
// fp16x2 split (main + mid@2^11), fold-8-steps. D transposed: row=vcol, col=hrow.
// Output (fp32): gates[rows*64] | ix[rows*8] | full[rows*64]

typedef __attribute__((ext_vector_type(8))) _Float16 f16x8;
typedef __attribute__((ext_vector_type(4))) float f32x4;
typedef unsigned int u32;

#define D_DIM 4096
#define WSTEP_BYTES 16384   // per-32k-step W image: 2 planes x 8KB

__device__ __forceinline__ float softplus_f(float x) {
    return fmaxf(x, 0.0f) + log1pf(expf(-fabsf(x)));
}

#define MFMA16F(A, B, C) __builtin_amdgcn_mfma_f32_16x16x32_f16((A), (B), (C), 0, 0, 0)

// ---- W pre-conversion (unchanged): 2 fp16 planes (p0=f16(w), p1=f16((w-p0)*2048)),
// per-32k-step 16KB image, chunk-swizzled sc = c4 ^ ((vrow>>2)&3)
__global__ __launch_bounds__(256)
void wconv_kernel(const float* __restrict__ Ww, const float* __restrict__ Wn,
                  char* __restrict__ Wp)
{
    const int bid = blockIdx.x;            // 256 blocks
    const int kc = bid >> 1, half = bid & 1;
    const int t = threadIdx.x;
    const int vrow = half * 64 + (t >> 2);
    const int c4 = t & 3;
    const float* src = (vrow < 64) ? (Ww + (size_t)vrow * D_DIM)
                                   : (Wn + (size_t)(vrow - 64) * D_DIM);
    const float4 a = *reinterpret_cast<const float4*>(src + kc * 32 + c4 * 8);
    const float4 b = *reinterpret_cast<const float4*>(src + kc * 32 + c4 * 8 + 4);
    const float f[8] = {a.x, a.y, a.z, a.w, b.x, b.y, b.z, b.w};
    union { _Float16 h[8]; uint4 q; } P0, P1;
#pragma unroll
    for (int i = 0; i < 8; ++i) {
        _Float16 lo = (_Float16)f[i];
        P0.h[i] = lo;
        P1.h[i] = (_Float16)((f[i] - (float)lo) * 2048.0f);
    }
    const int sc = c4 ^ ((vrow >> 2) & 3);
    char* dst = Wp + (size_t)kc * WSTEP_BYTES + vrow * 64 + sc * 16;
    *reinterpret_cast<uint4*>(dst)        = P0.q;
    *reinterpret_cast<uint4*>(dst + 8192) = P1.q;
}

__global__ __launch_bounds__(256, 4)
void router_kernel(const float* __restrict__ h,
                   const float* __restrict__ bw,
                   const float* __restrict__ bn,
                   const float* __restrict__ noise,
                   const char* __restrict__ Wp,
                   float* __restrict__ out_gates,
                   float* __restrict__ out_ix,
                   float* __restrict__ out_full)
{
    // h planes: [2 buf][2 plane][32 row][128B] = 16KB; epilogue reuses (16.6KB)
    __shared__ __align__(16) char smem[16896];

    const int t = threadIdx.x;
    const int lane = t & 63, w = t >> 6;    // 4 waves, wave w -> vcols w*32..+31
    const int c = lane & 15, kg = lane >> 4;
    const int row0 = blockIdx.x * 32;       // 1024 blocks

    // ---- h staging: thread t -> row t>>3, k-chunk (t&7)*8; 32B/step/thread ----
    const int hr = t >> 3, hc = t & 7;
    const float* hp = h + (size_t)(row0 + hr) * D_DIM + hc * 8;
    const int hwb = hr * 128 + ((hc ^ (hr & 7)) * 16);   // swizzled write byte off

#define HCONV(BUFBASE, V0, V1) {                                              \
        union { _Float16 q[8]; uint4 u; } Lo, Hi;                             \
        const float ff[8] = {V0.x, V0.y, V0.z, V0.w, V1.x, V1.y, V1.z, V1.w}; \
        _Pragma("unroll")                                                     \
        for (int i = 0; i < 8; ++i) {                                         \
            _Float16 lo = (_Float16)ff[i];                                    \
            Lo.q[i] = lo;                                                     \
            Hi.q[i] = (_Float16)((ff[i] - (float)lo) * 2048.0f);              \
        }                                                                     \
        *reinterpret_cast<uint4*>((BUFBASE) + hwb) = Lo.u;                    \
        *reinterpret_cast<uint4*>((BUFBASE) + 4096 + hwb) = Hi.u;             \
    }

    // ---- W A-frag per-lane offsets within a 16KB step image ----
    int woff[2][2];   // [vt][plane]; used with literal indices only
#pragma unroll
    for (int vt = 0; vt < 2; ++vt) {
        const int vrow = w * 32 + vt * 16 + c;
        const int sw = (kg ^ ((vrow >> 2) & 3)) * 16;
#pragma unroll
        for (int p = 0; p < 2; ++p) woff[vt][p] = p * 8192 + vrow * 64 + sw;
    }

    // ---- accumulators ----
    f32x4 grp[2][2], sAc[2][2], aM[2][2];   // [vt][jt]
#pragma unroll
    for (int vt = 0; vt < 2; ++vt)
#pragma unroll
        for (int jt = 0; jt < 2; ++jt) {
            grp[vt][jt] = (f32x4)0.0f; sAc[vt][jt] = (f32x4)0.0f;
            aM[vt][jt] = (f32x4)0.0f;
        }

    f16x8 WA00, WA01, WA10, WA11, WB00, WB01, WB10, WB11;

#define LOADW(S0, S1, S2, S3, IMG) {                                   \
        S0 = *reinterpret_cast<const f16x8*>((IMG) + woff[0][0]);      \
        S1 = *reinterpret_cast<const f16x8*>((IMG) + woff[0][1]);      \
        S2 = *reinterpret_cast<const f16x8*>((IMG) + woff[1][0]);      \
        S3 = *reinterpret_cast<const f16x8*>((IMG) + woff[1][1]);      \
    }

    // B-frag (h) read: byte = p*4096 + (jt*16+c)*128 + (((kh*4+kg)^(c&7))*16)
#define LOADB(VAR, HB, JT, P, KH)                                             \
    const f16x8 VAR = *reinterpret_cast<const f16x8*>(                        \
        (HB) + (P) * 4096 + ((JT) * 16 + c) * 128 + ((((KH) * 4 + kg) ^ (c & 7)) * 16));

#define COMPUTE(A0v0, A1v0, A0v1, A1v1, B00, B01, B10, B11)      \
        grp[0][0] = MFMA16F(A0v0, B00, grp[0][0]);               \
        aM[0][0]  = MFMA16F(A0v0, B01, aM[0][0]);                \
        aM[0][0]  = MFMA16F(A1v0, B00, aM[0][0]);                \
        grp[0][1] = MFMA16F(A0v0, B10, grp[0][1]);               \
        aM[0][1]  = MFMA16F(A0v0, B11, aM[0][1]);                \
        aM[0][1]  = MFMA16F(A1v0, B10, aM[0][1]);                \
        grp[1][0] = MFMA16F(A0v1, B00, grp[1][0]);               \
        aM[1][0]  = MFMA16F(A0v1, B01, aM[1][0]);                \
        aM[1][0]  = MFMA16F(A1v1, B00, aM[1][0]);                \
        grp[1][1] = MFMA16F(A0v1, B10, grp[1][1]);               \
        aM[1][1]  = MFMA16F(A0v1, B11, aM[1][1]);                \
        aM[1][1]  = MFMA16F(A1v1, B10, aM[1][1]);

    // ---- prologue: h step 0 -> buf0; WA <- (k-tile 0) ----
    {
        const float4 h0 = *reinterpret_cast<const float4*>(hp);
        const float4 h1 = *reinterpret_cast<const float4*>(hp + 4);
        LOADW(WA00, WA01, WA10, WA11, Wp);
        HCONV(smem, h0, h1);
    }
    asm volatile("s_waitcnt lgkmcnt(0)" ::: "memory");
    __builtin_amdgcn_sched_barrier(0);
    __builtin_amdgcn_s_barrier();
    __builtin_amdgcn_sched_barrier(0);

    // ---- main loop: 64 steps of BK=64 (2 k-tiles each), ONE barrier/step ----
    for (int s = 0; s < 64; ++s) {
        float4 nh0, nh1;
        const bool more = (s + 1 < 64);
        if (more) {   // issue next step's h loads (consumed at bottom)
            nh0 = *reinterpret_cast<const float4*>(hp + (s + 1) * 64);
            nh1 = *reinterpret_cast<const float4*>(hp + (s + 1) * 64 + 4);
        }
        char* hb = smem + (s & 1) * 8192;

        // k-half 0: prefetch WB <- k-tile (2s+1); compute with WA
        LOADW(WB00, WB01, WB10, WB11, Wp + (size_t)(2 * s + 1) * WSTEP_BYTES);
        LOADB(B00a, hb, 0, 0, 0)
        LOADB(B01a, hb, 0, 1, 0)
        LOADB(B10a, hb, 1, 0, 0)
        LOADB(B11a, hb, 1, 1, 0)
        COMPUTE(WA00, WA01, WA10, WA11, B00a, B01a, B10a, B11a)

        // k-half 1: prefetch WA <- k-tile (2s+2); compute with WB
        if (more) LOADW(WA00, WA01, WA10, WA11, Wp + (size_t)(2 * s + 2) * WSTEP_BYTES);
        LOADB(B00b, hb, 0, 0, 1)
        LOADB(B01b, hb, 0, 1, 1)
        LOADB(B10b, hb, 1, 0, 1)
        LOADB(B11b, hb, 1, 1, 1)
        COMPUTE(WB00, WB01, WB10, WB11, B00b, B01b, B10b, B11b)

        // fold main-term group every 8 steps (= 16 k-tiles, same as passing R8)
        if ((s & 7) == 7) {
#pragma unroll
            for (int vt = 0; vt < 2; ++vt)
#pragma unroll
                for (int jt = 0; jt < 2; ++jt) {
#pragma unroll
                    for (int e = 0; e < 4; ++e) sAc[vt][jt][e] += grp[vt][jt][e];
                    grp[vt][jt] = (f32x4)0.0f;
                }
        }

        // convert next step's h into the other buffer
        if (more) HCONV(smem + ((s + 1) & 1) * 8192, nh0, nh1);

        asm volatile("s_waitcnt lgkmcnt(0)" ::: "memory");
        __builtin_amdgcn_sched_barrier(0);
        __builtin_amdgcn_s_barrier();   // W loads stay in flight across it
        __builtin_amdgcn_sched_barrier(0);
    }

    // ---- logits -> LDS (D transposed: row=vcol-within-tile, col=h-row) ----
    float* lw_s = reinterpret_cast<float*>(smem);   // [32][65]
    float* ln_s = lw_s + 32 * 65;                   // [32][65]
    {
        float* dst = (w < 2) ? lw_s : ln_s;
        const int ebase = (w & 1) * 32;
#pragma unroll
        for (int vt = 0; vt < 2; ++vt)
#pragma unroll
            for (int jt = 0; jt < 2; ++jt)
#pragma unroll
                for (int r = 0; r < 4; ++r) {
                    const int e = ebase + vt * 16 + kg * 4 + r;
                    const int hrow = jt * 16 + c;
                    dst[hrow * 65 + e] = sAc[vt][jt][r] + aM[vt][jt][r] * 4.8828125e-4f;
                }
    }
    __syncthreads();

    // ---- noisy + top-8 + softmaxes: wave w -> rows w*8..w*8+7, lane = expert ----
    const float bwv = bw[lane];
    const float bnv = bn[lane];
    for (int q = 0; q < 8; ++q) {
        const int lrow = w * 8 + q;
        const int grow = row0 + lrow;
        const float lwv = lw_s[lrow * 65 + lane] + bwv;
        const float lnv = ln_s[lrow * 65 + lane] + bnv;
        const float nz  = noise[(size_t)grow * 64 + lane];
        const float v   = lwv + nz * softplus_f(lnv);

        float cur2 = v;
        float m8 = 0.0f;
        int winIdx = 0;
        bool picked = false;
#pragma unroll
        for (int r = 0; r < 8; ++r) {
            float bvv = cur2;
            int   bi  = lane;
#pragma unroll
            for (int off = 32; off; off >>= 1) {
                const float ov = __shfl_xor(bvv, off);
                const int   oi = __shfl_xor(bi, off);
                if (ov > bvv || (ov == bvv && oi < bi)) { bvv = ov; bi = oi; }
            }
            if (r == 0) m8 = bvv;
            if (lane == r) winIdx = bi;
            if (lane == bi) { picked = true; cur2 = -INFINITY; }
        }

        const float pf = expf(v - m8);
        const float pg = picked ? pf : 0.0f;
        float sf = pf, sg = pg;
#pragma unroll
        for (int off = 32; off; off >>= 1) {
            sf += __shfl_xor(sf, off);
            sg += __shfl_xor(sg, off);
        }

        out_full [(size_t)grow * 64 + lane] = pf / sf;
        out_gates[(size_t)grow * 64 + lane] = pg / sg;
        if (lane < 8) out_ix[(size_t)grow * 8 + lane] = (float)winIdx;
    }
}

extern "C" void kernel_launch(void* const* d_in, const int* in_sizes, int n_in,
                              void* d_out, int out_size, void* d_ws, size_t ws_size,
                              hipStream_t stream) {
    const float* h  = (const float*)d_in[0];
    const float* Ww = (const float*)d_in[1];
    const float* bw = (const float*)d_in[2];
    const float* Wn = (const float*)d_in[3];
    const float* bn = (const float*)d_in[4];
    const float* nz = (const float*)d_in[5];

    const int rows = in_sizes[5] / 64;   // 32768

    float* out = (float*)d_out;
    float* og = out;
    float* oi = out + (size_t)rows * 64;
    float* of = out + (size_t)rows * 64 + (size_t)rows * 8;

    char* Wp = (char*)d_ws;   // 128 k-tiles * 16384 B = 2 MB

    hipLaunchKernelGGL(wconv_kernel, dim3(256), dim3(256), 0, stream, Ww, Wn, Wp);
    hipLaunchKernelGGL(router_kernel, dim3(rows / 32), dim3(256), 0, stream,
                       h, bw, bn, nz, Wp, og, oi, of);
}